// Round 8
// baseline (204.988 us; speedup 1.0000x reference)
//
#include <hip/hip_runtime.h>
#include <math.h>

#define NTOK 16384
#define DIM  4096
#define NE   64
#define TOPK 8
#define CHUNK 256                 // floats per row per chunk
#define NCH  (DIM / CHUNK)        // 16 chunks
#define SLC  (CHUNK / 32)         // 8 k32-slices per chunk
#define ROUTE_SCALE 2.5f

typedef __attribute__((ext_vector_type(8))) short short8v;
typedef __attribute__((ext_vector_type(4))) float f32x4;

// exact 3-term bf16 truncation split of 8 f32, packed as 3x short8 (bf16) frags
__device__ __forceinline__ void split3_pack(const float* v, uint4& b0, uint4& b1, uint4& b2)
{
    uint p0[8], p1[8], p2[8];
#pragma unroll
    for (int j = 0; j < 8; ++j) {
        const float xv = v[j];
        const uint  u0 = __float_as_uint(xv) & 0xffff0000u;
        const float f0 = __uint_as_float(u0);
        const float r  = xv - f0;                       // exact
        const uint  u1 = __float_as_uint(r) & 0xffff0000u;
        const float f1 = __uint_as_float(u1);
        const float r2 = r - f1;                        // exact, fits bf16
        const uint  u2 = __float_as_uint(r2) & 0xffff0000u;
        p0[j] = u0; p1[j] = u1; p2[j] = u2;
    }
    b0 = make_uint4(p0[1] | (p0[0] >> 16), p0[3] | (p0[2] >> 16),
                    p0[5] | (p0[4] >> 16), p0[7] | (p0[6] >> 16));
    b1 = make_uint4(p1[1] | (p1[0] >> 16), p1[3] | (p1[2] >> 16),
                    p1[5] | (p1[4] >> 16), p1[7] | (p1[6] >> 16));
    b2 = make_uint4(p2[1] | (p2[0] >> 16), p2[3] | (p2[2] >> 16),
                    p2[5] | (p2[4] >> 16), p2[7] | (p2[6] >> 16));
}

// ---- prep: w -> frag-ready bf16 splits. entry(ks,nt,sp,lane) at (ks*12 + nt*3+sp)*64+lane
__global__ __launch_bounds__(256)
void prep_w(const float* __restrict__ gw, uint4* __restrict__ wS)
{
    const int tid  = blockIdx.x * 256 + threadIdx.x;   // 32768 total
    const int lane = tid & 63;
    const int nt   = (tid >> 6) & 3;
    const int ks   = tid >> 8;                         // 0..127
    const int e    = nt * 16 + (lane & 15);
    const int kb   = ks * 32 + (lane >> 4) * 8;
    float v[8];
    *(float4*)&v[0] = *(const float4*)&gw[(size_t)e * DIM + kb];
    *(float4*)&v[4] = *(const float4*)&gw[(size_t)e * DIM + kb + 4];
    uint4 b0, b1, b2;
    split3_pack(v, b0, b1, b2);
    const size_t base = (size_t)(ks * 4 + nt) * 3 * 64 + lane;
    wS[base] = b0; wS[base + 64] = b1; wS[base + 128] = b2;
}

// ---- fused: 8-wave WG, 64 tokens; LDS-staged x (1KB row bursts), full-k per wave ----
// wave = (token-group tg 0..3) x (expert-half eh 0..1): 16 tokens x 32 experts each.
__global__ __launch_bounds__(512, 2)
void router_fused(const float* __restrict__ x, const uint4* __restrict__ wS,
                  const float* __restrict__ bias, float* __restrict__ out)
{
    __shared__ float xs[2][64][CHUNK];      // 128 KB, double-buffered x tile
    __shared__ float sc[64][NE + 1];        // sigmoid scores
    __shared__ int   hist[NE];

    const int t    = threadIdx.x;
    const int lane = t & 63;
    const int wv   = __builtin_amdgcn_readfirstlane(t >> 6);   // 0..7
    const int r15  = lane & 15;
    const int g    = lane >> 4;
    const int tg   = wv & 3;                // token group
    const int eh   = wv >> 2;               // expert half
    const int tok0 = blockIdx.x * 64;

    if (t < NE) hist[t] = 0;

    const int row = tg * 16 + r15;          // A-frag row this lane reads
    const int sw  = r15 & 7;                // read-side XOR-swizzle key (row & 7)
    // staging: wave stages rows wv*8..wv*8+7; one 1KB-burst load per row
    const float* xstage = x + (size_t)(tok0 + wv * 8) * DIM + lane * 4;
    const uint4* wB = wS + (size_t)(eh * 6) * 64 + lane;

    f32x4 acc[2];
    acc[0] = (f32x4){0.f, 0.f, 0.f, 0.f};
    acc[1] = (f32x4){0.f, 0.f, 0.f, 0.f};

    float4 st[8];
    uint4  b[4][6];                         // rotating 4-slice B buffer

    // prologue: stage chunk 0 (load 1KB bursts -> swizzled ds_write)
#pragma unroll
    for (int i = 0; i < 8; ++i)
        st[i] = *(const float4*)(xstage + (size_t)i * DIM);
#pragma unroll
    for (int i = 0; i < 8; ++i)
        *(float4*)&xs[0][wv * 8 + i][(lane ^ i) * 4] = st[i];

    for (int c = 0; c < NCH; ++c) {
        const int  cb   = c & 1;
        const bool more = (c + 1 < NCH);
        __syncthreads();    // everyone done with buf cb^1 reads + my stage writes visible
        // B for slices 0..3 (issued BEFORE stage loads: computing s0..3 never drains stage)
#pragma unroll
        for (int s = 0; s < 4; ++s)
#pragma unroll
            for (int j = 0; j < 6; ++j)
                b[s][j] = wB[((size_t)(c * SLC + s) * 12 + j) * 64];
        // stage loads for chunk c+1 (1 KB contiguous per row)
        if (more) {
#pragma unroll
            for (int i = 0; i < 8; ++i)
                st[i] = *(const float4*)(xstage + (size_t)i * DIM + (size_t)(c + 1) * CHUNK);
        }
#pragma unroll
        for (int s = 0; s < SLC; ++s) {
            // A frag: two swizzled b128 reads (conflict-free by construction)
            float a8[8];
            const int G0 = s * 8 + g * 2;
            *(float4*)&a8[0] = *(const float4*)&xs[cb][row][(G0 ^ sw) * 4];
            *(float4*)&a8[4] = *(const float4*)&xs[cb][row][((G0 + 1) ^ sw) * 4];
            uint4 a0u, a1u, a2u;
            split3_pack(a8, a0u, a1u, a2u);
            const short8v a0 = *(short8v*)&a0u;
            const short8v a1 = *(short8v*)&a1u;
            const short8v a2 = *(short8v*)&a2u;
#pragma unroll
            for (int ntl = 0; ntl < 2; ++ntl) {
                const short8v b0 = *(const short8v*)&b[s & 3][ntl * 3 + 0];
                const short8v b1 = *(const short8v*)&b[s & 3][ntl * 3 + 1];
                const short8v b2 = *(const short8v*)&b[s & 3][ntl * 3 + 2];
                f32x4 cc = acc[ntl];
                cc = __builtin_amdgcn_mfma_f32_16x16x32_bf16(a2, b0, cc, 0, 0, 0);
                cc = __builtin_amdgcn_mfma_f32_16x16x32_bf16(a1, b1, cc, 0, 0, 0);
                cc = __builtin_amdgcn_mfma_f32_16x16x32_bf16(a0, b2, cc, 0, 0, 0);
                cc = __builtin_amdgcn_mfma_f32_16x16x32_bf16(a1, b0, cc, 0, 0, 0);
                cc = __builtin_amdgcn_mfma_f32_16x16x32_bf16(a0, b1, cc, 0, 0, 0);
                cc = __builtin_amdgcn_mfma_f32_16x16x32_bf16(a0, b0, cc, 0, 0, 0);
                acc[ntl] = cc;
            }
            // B prefetch for slice s+4 (slot s&3 just consumed)
            if (s < 4) {
#pragma unroll
                for (int j = 0; j < 6; ++j)
                    b[s & 3][j] = wB[((size_t)(c * SLC + s + 4) * 12 + j) * 64];
            }
            // swizzled ds_write of staged chunk (stage loads have ~5 slices of lead)
            if (s == 5 && more) {
#pragma unroll
                for (int i = 0; i < 8; ++i)
                    *(float4*)&xs[cb ^ 1][wv * 8 + i][(lane ^ i) * 4] = st[i];
            }
        }
    }

    // ---- scores -> LDS (C/D layout proven r4-7: token = g*4+q, expert-low = r15) ----
#pragma unroll
    for (int ntl = 0; ntl < 2; ++ntl)
#pragma unroll
        for (int q = 0; q < 4; ++q)
            sc[tg * 16 + g * 4 + q][eh * 32 + ntl * 16 + r15] =
                1.f / (1.f + expf(-acc[ntl][q]));
    __syncthreads();

    // ---- top-8: wave wv handles tokens wv*8..wv*8+7; lane == expert (proven code) ----
    const float bias_l = bias[lane];
#pragma unroll 1
    for (int i = 0; i < 8; ++i) {
        const int tok = wv * 8 + i;
        const float s = sc[tok][lane];
        float myv  = s + bias_l;
        float outv = 0.f;
        int   outi = 0;
        float sum  = 0.f;
#pragma unroll
        for (int k = 0; k < TOPK; ++k) {
            float cv = myv;
            int   ci = lane;
#pragma unroll
            for (int off = 32; off; off >>= 1) {
                float ov = __shfl_xor(cv, off, 64);
                int   oi = __shfl_xor(ci, off, 64);
                if (ov > cv || (ov == cv && oi < ci)) { cv = ov; ci = oi; }
            }
            float ts = __shfl(s, ci, 64);      // unbiased score of winner
            sum += ts;
            if (lane == k)  { outv = ts; outi = ci; }
            if (lane == ci) { myv = -1e30f; }
        }
        const float denom = sum + 1e-20f;
        const size_t gt = (size_t)tok0 + tok;
        if (lane < TOPK) {
            out[gt * TOPK + lane] = (outv / denom) * ROUTE_SCALE;
            out[(size_t)NTOK * TOPK + gt * TOPK + lane] = (float)outi;
            atomicAdd(&hist[outi], 1);
        }
    }

    __syncthreads();
    if (t < NE) {
        int cgt = hist[t];
        if (cgt) atomicAdd(&out[(size_t)NTOK * TOPK * 2 + t], (float)cgt);
    }
}

extern "C" void kernel_launch(void* const* d_in, const int* in_sizes, int n_in,
                              void* d_out, int out_size, void* d_ws, size_t ws_size,
                              hipStream_t stream)
{
    const float* x    = (const float*)d_in[0];
    const float* gw   = (const float*)d_in[1];
    const float* bias = (const float*)d_in[2];
    float* out = (float*)d_out;
    uint4* wS  = (uint4*)d_ws;   // 1.5 MB

    // histogram region must start at zero every call
    hipMemsetAsync(out + (size_t)NTOK * TOPK * 2, 0, NE * sizeof(float), stream);

    prep_w<<<128, 256, 0, stream>>>(gw, wS);
    router_fused<<<NTOK / 64, 512, 0, stream>>>(x, wS, bias, out);
}

// Round 9
// 112.413 us; speedup vs baseline: 1.8235x; 1.8235x over previous
//
#include <hip/hip_runtime.h>
#include <math.h>

#define NTOK 16384
#define DIM  4096
#define NE   64
#define TOPK 8
#define TPB  32                  // tokens per block
#define CHUNK 128                // f32 elems per row per chunk
#define NCH  (DIM / CHUNK)       // 32 chunks, 4 k32-slices each
#define ROUTE_SCALE 2.5f

typedef __attribute__((ext_vector_type(8))) short short8v;
typedef __attribute__((ext_vector_type(4))) float f32x4;

// exact 3-term bf16 truncation split of 8 f32, packed as 3x short8 (bf16) frags
__device__ __forceinline__ void split3_pack(const float* v, uint4& b0, uint4& b1, uint4& b2)
{
    uint p0[8], p1[8], p2[8];
#pragma unroll
    for (int j = 0; j < 8; ++j) {
        const float xv = v[j];
        const uint  u0 = __float_as_uint(xv) & 0xffff0000u;
        const float f0 = __uint_as_float(u0);
        const float r  = xv - f0;                       // exact
        const uint  u1 = __float_as_uint(r) & 0xffff0000u;
        const float f1 = __uint_as_float(u1);
        const float r2 = r - f1;                        // exact, fits bf16
        const uint  u2 = __float_as_uint(r2) & 0xffff0000u;
        p0[j] = u0; p1[j] = u1; p2[j] = u2;
    }
    b0 = make_uint4(p0[1] | (p0[0] >> 16), p0[3] | (p0[2] >> 16),
                    p0[5] | (p0[4] >> 16), p0[7] | (p0[6] >> 16));
    b1 = make_uint4(p1[1] | (p1[0] >> 16), p1[3] | (p1[2] >> 16),
                    p1[5] | (p1[4] >> 16), p1[7] | (p1[6] >> 16));
    b2 = make_uint4(p2[1] | (p2[0] >> 16), p2[3] | (p2[2] >> 16),
                    p2[5] | (p2[4] >> 16), p2[7] | (p2[6] >> 16));
}

// 4-elem variant for the LDS-plane staging path
__device__ __forceinline__ void split3_pack4(const float4 v, uint2& q0, uint2& q1, uint2& q2)
{
    const float vv[4] = {v.x, v.y, v.z, v.w};
    uint p0[4], p1[4], p2[4];
#pragma unroll
    for (int j = 0; j < 4; ++j) {
        const float xv = vv[j];
        const uint  u0 = __float_as_uint(xv) & 0xffff0000u;
        const float f0 = __uint_as_float(u0);
        const float r  = xv - f0;
        const uint  u1 = __float_as_uint(r) & 0xffff0000u;
        const float f1 = __uint_as_float(u1);
        const float r2 = r - f1;
        const uint  u2 = __float_as_uint(r2) & 0xffff0000u;
        p0[j] = u0; p1[j] = u1; p2[j] = u2;
    }
    q0 = make_uint2(p0[1] | (p0[0] >> 16), p0[3] | (p0[2] >> 16));
    q1 = make_uint2(p1[1] | (p1[0] >> 16), p1[3] | (p1[2] >> 16));
    q2 = make_uint2(p2[1] | (p2[0] >> 16), p2[3] | (p2[2] >> 16));
}

// ---- prep: w -> frag-ready bf16 splits (UNCHANGED, proven r4-r8) ----
__global__ __launch_bounds__(256)
void prep_w(const float* __restrict__ gw, uint4* __restrict__ wS)
{
    const int tid  = blockIdx.x * 256 + threadIdx.x;   // 32768 total
    const int lane = tid & 63;
    const int nt   = (tid >> 6) & 3;
    const int ks   = tid >> 8;                         // 0..127
    const int e    = nt * 16 + (lane & 15);
    const int kb   = ks * 32 + (lane >> 4) * 8;
    float v[8];
    *(float4*)&v[0] = *(const float4*)&gw[(size_t)e * DIM + kb];
    *(float4*)&v[4] = *(const float4*)&gw[(size_t)e * DIM + kb + 4];
    uint4 b0, b1, b2;
    split3_pack(v, b0, b1, b2);
    const size_t base = (size_t)(ks * 4 + nt) * 3 * 64 + lane;
    wS[base] = b0; wS[base + 64] = b1; wS[base + 128] = b2;
}

#define MFMA6(A0, A1, A2, B0, B1, B2, ACC) do {                              \
    ACC = __builtin_amdgcn_mfma_f32_16x16x32_bf16(A2, B0, ACC, 0, 0, 0);     \
    ACC = __builtin_amdgcn_mfma_f32_16x16x32_bf16(A1, B1, ACC, 0, 0, 0);     \
    ACC = __builtin_amdgcn_mfma_f32_16x16x32_bf16(A0, B2, ACC, 0, 0, 0);     \
    ACC = __builtin_amdgcn_mfma_f32_16x16x32_bf16(A1, B0, ACC, 0, 0, 0);     \
    ACC = __builtin_amdgcn_mfma_f32_16x16x32_bf16(A0, B1, ACC, 0, 0, 0);     \
    ACC = __builtin_amdgcn_mfma_f32_16x16x32_bf16(A0, B0, ACC, 0, 0, 0);     \
} while (0)

// ---- fused: 4-wave WG, 32 tokens; x split once -> bf16 planes in LDS ----
// wave = expert quarter (nt). Each wave: 32 tok x 16 exp, acc = 8 VGPR.
__global__ __launch_bounds__(256, 2)
void router_fused(const float* __restrict__ x, const uint4* __restrict__ wS,
                  const float* __restrict__ bias, float* __restrict__ out)
{
    __shared__ ushort xp[2][3][TPB][CHUNK];   // 48 KB: dbuf x 3 planes (hi,mid,lo)
    __shared__ float  sc[TPB][NE + 1];        // 8.3 KB
    __shared__ int    hist[NE];

    const int t    = threadIdx.x;
    const int lane = t & 63;
    const int wv   = __builtin_amdgcn_readfirstlane(t >> 6);   // 0..3 = expert quarter
    const int r15  = lane & 15;
    const int g    = lane >> 4;
    const int tok0 = blockIdx.x * TPB;

    if (t < NE) hist[t] = 0;

    // staging map: thread -> row (t>>3), f32 granule base (t&7); granules +8j
    const int srow = t >> 3;
    const int sg   = t & 7;
    const float* xsrc = x + (size_t)(tok0 + srow) * DIM + sg * 4;

    const uint4* wB = wS + wv * 192 + lane;   // this wave's expert quarter

    f32x4 acc0 = {0.f, 0.f, 0.f, 0.f};
    f32x4 acc1 = {0.f, 0.f, 0.f, 0.f};
    uint4  B0[12], B1[12];
    float4 stP[4], stQ[4];

#define STAGE_LOAD(ST, c1) do {                                              \
        _Pragma("unroll")                                                    \
        for (int j = 0; j < 4; ++j)                                          \
            ST[j] = *(const float4*)(xsrc + (size_t)(c1) * CHUNK + j * 32);  \
    } while (0)

// swizzled bf16-plane write: 16B-granule H = G ^ (row&15)
#define STAGE_WRITE(ST, bb) do {                                             \
        _Pragma("unroll")                                                    \
        for (int j = 0; j < 4; ++j) {                                        \
            uint2 q0, q1, q2;                                                \
            split3_pack4(ST[j], q0, q1, q2);                                 \
            const int gg  = sg + 8 * j;                                      \
            const int off = (((gg >> 1) ^ (srow & 15)) << 3) + ((gg & 1) << 2); \
            *(uint2*)&xp[bb][0][srow][off] = q0;                             \
            *(uint2*)&xp[bb][1][srow][off] = q1;                             \
            *(uint2*)&xp[bb][2][srow][off] = q2;                             \
        }                                                                    \
    } while (0)

#define LOADB(B, c1) do {                                                    \
        _Pragma("unroll")                                                    \
        for (int s2 = 0; s2 < 4; ++s2)                                       \
            _Pragma("unroll")                                                \
            for (int sp = 0; sp < 3; ++sp)                                   \
                B[s2 * 3 + sp] = wB[(size_t)((c1) * 4 + s2) * 768 + sp * 64];\
    } while (0)

#define SLICE(B, cb, s) do {                                                 \
        const int off = ((((s) * 4 + g) ^ r15) << 3);                        \
        const short8v a0_0 = *(const short8v*)&xp[cb][0][r15][off];          \
        const short8v a1_0 = *(const short8v*)&xp[cb][1][r15][off];          \
        const short8v a2_0 = *(const short8v*)&xp[cb][2][r15][off];          \
        const short8v a0_1 = *(const short8v*)&xp[cb][0][16 + r15][off];     \
        const short8v a1_1 = *(const short8v*)&xp[cb][1][16 + r15][off];     \
        const short8v a2_1 = *(const short8v*)&xp[cb][2][16 + r15][off];     \
        const short8v b0 = *(const short8v*)&B[(s) * 3 + 0];                 \
        const short8v b1 = *(const short8v*)&B[(s) * 3 + 1];                 \
        const short8v b2 = *(const short8v*)&B[(s) * 3 + 2];                 \
        MFMA6(a0_0, a1_0, a2_0, b0, b1, b2, acc0);                           \
        MFMA6(a0_1, a1_1, a2_1, b0, b1, b2, acc1);                           \
    } while (0)

#define CHUNK_BODY(c, BU, BV, STW, STL) do {                                 \
        __syncthreads();                                                     \
        SLICE(BU, (c) & 1, 0);                                               \
        SLICE(BU, (c) & 1, 1);                                               \
        SLICE(BU, (c) & 1, 2);                                               \
        SLICE(BU, (c) & 1, 3);                                               \
        if ((c) + 1 < NCH) { LOADB(BV, (c) + 1); STAGE_WRITE(STW, ((c) & 1) ^ 1); } \
        if ((c) + 2 < NCH) { STAGE_LOAD(STL, (c) + 2); }                     \
    } while (0)

    // prologue: B(0) first (oldest in FIFO -> its wait never blocks on HBM)
    LOADB(B0, 0);
    STAGE_LOAD(stP, 0);
    STAGE_WRITE(stP, 0);
    STAGE_LOAD(stP, 1);

    for (int c = 0; c < NCH; c += 2) {
        CHUNK_BODY(c,     B0, B1, stP, stQ);
        CHUNK_BODY(c + 1, B1, B0, stQ, stP);
    }
#undef STAGE_LOAD
#undef STAGE_WRITE
#undef LOADB
#undef SLICE
#undef CHUNK_BODY

    // ---- scores (C/D layout proven r4-r8: token = T*16 + g*4 + q, expert = wv*16 + r15)
#pragma unroll
    for (int q = 0; q < 4; ++q) {
        sc[g * 4 + q][wv * 16 + r15]      = 1.f / (1.f + expf(-acc0[q]));
        sc[16 + g * 4 + q][wv * 16 + r15] = 1.f / (1.f + expf(-acc1[q]));
    }
    __syncthreads();

    // ---- top-8: wave wv handles tokens wv*8..wv*8+7; lane == expert (proven) ----
    const float bias_l = bias[lane];
#pragma unroll 1
    for (int i = 0; i < 8; ++i) {
        const int tok = wv * 8 + i;
        const float s = sc[tok][lane];
        float myv  = s + bias_l;
        float outv = 0.f;
        int   outi = 0;
        float sum  = 0.f;
#pragma unroll
        for (int k = 0; k < TOPK; ++k) {
            float cv = myv;
            int   ci = lane;
#pragma unroll
            for (int off = 32; off; off >>= 1) {
                float ov = __shfl_xor(cv, off, 64);
                int   oi = __shfl_xor(ci, off, 64);
                if (ov > cv || (ov == cv && oi < ci)) { cv = ov; ci = oi; }
            }
            float ts = __shfl(s, ci, 64);      // unbiased score of winner
            sum += ts;
            if (lane == k)  { outv = ts; outi = ci; }
            if (lane == ci) { myv = -1e30f; }
        }
        const float denom = sum + 1e-20f;
        const size_t gt = (size_t)tok0 + tok;
        if (lane < TOPK) {
            out[gt * TOPK + lane] = (outv / denom) * ROUTE_SCALE;
            out[(size_t)NTOK * TOPK + gt * TOPK + lane] = (float)outi;
            atomicAdd(&hist[outi], 1);
        }
    }

    __syncthreads();
    if (t < NE) {
        int cgt = hist[t];
        if (cgt) atomicAdd(&out[(size_t)NTOK * TOPK * 2 + t], (float)cgt);
    }
}

extern "C" void kernel_launch(void* const* d_in, const int* in_sizes, int n_in,
                              void* d_out, int out_size, void* d_ws, size_t ws_size,
                              hipStream_t stream)
{
    const float* x    = (const float*)d_in[0];
    const float* gw   = (const float*)d_in[1];
    const float* bias = (const float*)d_in[2];
    float* out = (float*)d_out;
    uint4* wS  = (uint4*)d_ws;   // 1.5 MB

    // histogram region must start at zero every call
    hipMemsetAsync(out + (size_t)NTOK * TOPK * 2, 0, NE * sizeof(float), stream);

    prep_w<<<128, 256, 0, stream>>>(gw, wS);
    router_fused<<<NTOK / TPB, 256, 0, stream>>>(x, wS, bias, out);
}